// Round 11
// baseline (130.107 us; speedup 1.0000x reference)
//
#include <hip/hip_runtime.h>

// PointPillarScatter: out[b][c][y][x] = pf[b][p][c] where coords[b][p] = (b,0,y,x), else 0.
// B=8, P=20000, C=64, NX=432, NY=496. Output (8,64,496,432) fp32.
//
// Gather formulation (R9 structure, init-free):
//   K1 (scatter): map16[b][y*NX+x] = p  — no clearing pass; XCD-chunked so map
//       writes land in the L2 of the XCD whose gather blocks will read them.
//   K2 (gather): each thread owns TWO independent 4-cell quads (i4 and
//       i4 + NCELL4/2): same coalesced u16x4 map reads, same exec-masked
//       conditional pf loads, same full-density NT store streams as R9 —
//       but half the threads, so half the dependent map->coords->pf prologue
//       chains, with 2x ILP to overlap them.
//       Reverse-check validation: entry q used only if q < P and coords[b][q]
//       maps back to this cell -> correct for arbitrary ws junk.
//       NT stores (R8 A/B: plain +21us). u16 map. 64-thr blocks.

#define BB    8
#define PP    20000
#define CC    64
#define NXX   432
#define NYY   496
#define NCELL (NXX * NYY)   /* 214272 */
#define NCELL4 (NCELL / 4)  /* 53568  */
#define HALF4 (NCELL4 / 2)  /* 26784: quads per half-canvas */

#define GBLK   64
#define GNWG   ((BB * HALF4) / GBLK)   /* 8*26784/64 = 3348 blocks */
#define NXCD   8
/* 3348 = 8*418 + 4 -> bijective remainder chunking */
#define SWZ_Q  (GNWG / NXCD)           /* 418 */
#define SWZ_R  (GNWG % NXCD)           /* 4   */

#define SNWG   ((BB * PP) / GBLK)      /* scatter: 160000/64 = 2500 blocks */
#define SSWZ_Q (SNWG / NXCD)           /* 312 */
#define SSWZ_R (SNWG % NXCD)           /* 4   */

typedef float f32x4 __attribute__((ext_vector_type(4)));
typedef unsigned short u16;
typedef u16 u16x4 __attribute__((ext_vector_type(4)));

__device__ __forceinline__ int xcd_chunk(int bid, int q, int r) {
    int xcd = bid % NXCD, idx = bid / NXCD;
    return (xcd < r ? xcd * (q + 1) : r * (q + 1) + (xcd - r) * q) + idx;
}

__global__ void __launch_bounds__(GBLK) ppsc_scatter_map(const int* __restrict__ coords,
                                                         u16* __restrict__ map16) {
    int wg = xcd_chunk(blockIdx.x, SSWZ_Q, SSWZ_R);
    int t  = wg * GBLK + threadIdx.x;          // one thread per (b,p)
    int b  = t / PP;
    int p  = t - b * PP;
    const int4 c4 = ((const int4*)coords)[t];  // [b, z, y, x] as int32
    int y = c4.z, x = c4.w;
    if ((unsigned)y < (unsigned)NYY && (unsigned)x < (unsigned)NXX)
        map16[(size_t)b * NCELL + y * NXX + x] = (u16)p;
}

// each thread: quads i4 and i4+HALF4 of batch b, all 64 channels.
__global__ void __launch_bounds__(GBLK, 8) ppsc_gather_all(const float* __restrict__ pf,
                                                           const u16* __restrict__ map16,
                                                           const int* __restrict__ coords,
                                                           float* __restrict__ out) {
    int wg = xcd_chunk(blockIdx.x, SWZ_Q, SWZ_R);
    int t  = wg * GBLK + threadIdx.x;
    int i4 = t % HALF4;
    int b  = t / HALF4;

    const u16x4* mrow = (const u16x4*)(map16 + (size_t)b * NCELL);
    u16x4 mA = mrow[i4];
    u16x4 mB = mrow[i4 + HALF4];
    const int4* cb = ((const int4*)coords) + (size_t)b * PP;
    int cellA = i4 * 4;
    int cellB = (i4 + HALF4) * 4;

    // reverse-validate: junk-proof, init-free.
    bool a0 = (mA.x < PP), a1 = (mA.y < PP), a2 = (mA.z < PP), a3 = (mA.w < PP);
    bool b0 = (mB.x < PP), b1 = (mB.y < PP), b2 = (mB.z < PP), b3 = (mB.w < PP);
    if (a0) { int4 c = cb[mA.x]; a0 = (c.z * NXX + c.w) == cellA;     }
    if (a1) { int4 c = cb[mA.y]; a1 = (c.z * NXX + c.w) == cellA + 1; }
    if (a2) { int4 c = cb[mA.z]; a2 = (c.z * NXX + c.w) == cellA + 2; }
    if (a3) { int4 c = cb[mA.w]; a3 = (c.z * NXX + c.w) == cellA + 3; }
    if (b0) { int4 c = cb[mB.x]; b0 = (c.z * NXX + c.w) == cellB;     }
    if (b1) { int4 c = cb[mB.y]; b1 = (c.z * NXX + c.w) == cellB + 1; }
    if (b2) { int4 c = cb[mB.z]; b2 = (c.z * NXX + c.w) == cellB + 2; }
    if (b3) { int4 c = cb[mB.w]; b3 = (c.z * NXX + c.w) == cellB + 3; }

    const float* base = pf + (size_t)b * PP * CC;
    const float* pa0 = base + (size_t)mA.x * CC;
    const float* pa1 = base + (size_t)mA.y * CC;
    const float* pa2 = base + (size_t)mA.z * CC;
    const float* pa3 = base + (size_t)mA.w * CC;
    const float* pb0 = base + (size_t)mB.x * CC;
    const float* pb1 = base + (size_t)mB.y * CC;
    const float* pb2 = base + (size_t)mB.z * CC;
    const float* pb3 = base + (size_t)mB.w * CC;

    float* obA = out + (size_t)b * CC * NCELL + (size_t)cellA;
    float* obB = out + (size_t)b * CC * NCELL + (size_t)cellB;

#pragma unroll 4
    for (int cq = 0; cq < 16; ++cq) {
        f32x4 oA0 = (f32x4)0.f, oA1 = (f32x4)0.f, oA2 = (f32x4)0.f, oA3 = (f32x4)0.f;
        f32x4 oB0 = (f32x4)0.f, oB1 = (f32x4)0.f, oB2 = (f32x4)0.f, oB3 = (f32x4)0.f;
        if (a0) { f32x4 f = *(const f32x4*)(pa0 + cq * 4);
                  oA0.x = f.x; oA1.x = f.y; oA2.x = f.z; oA3.x = f.w; }
        if (a1) { f32x4 f = *(const f32x4*)(pa1 + cq * 4);
                  oA0.y = f.x; oA1.y = f.y; oA2.y = f.z; oA3.y = f.w; }
        if (a2) { f32x4 f = *(const f32x4*)(pa2 + cq * 4);
                  oA0.z = f.x; oA1.z = f.y; oA2.z = f.z; oA3.z = f.w; }
        if (a3) { f32x4 f = *(const f32x4*)(pa3 + cq * 4);
                  oA0.w = f.x; oA1.w = f.y; oA2.w = f.z; oA3.w = f.w; }
        if (b0) { f32x4 f = *(const f32x4*)(pb0 + cq * 4);
                  oB0.x = f.x; oB1.x = f.y; oB2.x = f.z; oB3.x = f.w; }
        if (b1) { f32x4 f = *(const f32x4*)(pb1 + cq * 4);
                  oB0.y = f.x; oB1.y = f.y; oB2.y = f.z; oB3.y = f.w; }
        if (b2) { f32x4 f = *(const f32x4*)(pb2 + cq * 4);
                  oB0.z = f.x; oB1.z = f.y; oB2.z = f.z; oB3.z = f.w; }
        if (b3) { f32x4 f = *(const f32x4*)(pb3 + cq * 4);
                  oB0.w = f.x; oB1.w = f.y; oB2.w = f.z; oB3.w = f.w; }
        float* opA = obA + (size_t)(cq * 4) * NCELL;
        float* opB = obB + (size_t)(cq * 4) * NCELL;
        __builtin_nontemporal_store(oA0, (f32x4*)opA);
        __builtin_nontemporal_store(oA1, (f32x4*)(opA + (size_t)NCELL));
        __builtin_nontemporal_store(oA2, (f32x4*)(opA + 2 * (size_t)NCELL));
        __builtin_nontemporal_store(oA3, (f32x4*)(opA + 3 * (size_t)NCELL));
        __builtin_nontemporal_store(oB0, (f32x4*)opB);
        __builtin_nontemporal_store(oB1, (f32x4*)(opB + (size_t)NCELL));
        __builtin_nontemporal_store(oB2, (f32x4*)(opB + 2 * (size_t)NCELL));
        __builtin_nontemporal_store(oB3, (f32x4*)(opB + 3 * (size_t)NCELL));
    }
}

// ---- fallback path (ws too small): zero output + direct scatter ----
__global__ void ppsc_zero(float* __restrict__ out, int n4) {
    int t = blockIdx.x * blockDim.x + threadIdx.x;
    if (t < n4) ((float4*)out)[t] = make_float4(0.f, 0.f, 0.f, 0.f);
}

__global__ void ppsc_direct_scatter(const float* __restrict__ pf,
                                    const int* __restrict__ coords,
                                    float* __restrict__ out) {
    int t = blockIdx.x * blockDim.x + threadIdx.x;  // one thread per (b,p,c)
    if (t >= BB * PP * CC) return;
    int c  = t % CC;
    int bp = t / CC;
    int b  = bp / PP;
    const int* cd = coords + (size_t)bp * 4;
    int y = cd[2], x = cd[3];
    if ((unsigned)y < (unsigned)NYY && (unsigned)x < (unsigned)NXX)
        out[((size_t)(b * CC + c)) * NCELL + (size_t)y * NXX + x] = pf[(size_t)bp * CC + c];
}

extern "C" void kernel_launch(void* const* d_in, const int* in_sizes, int n_in,
                              void* d_out, int out_size, void* d_ws, size_t ws_size,
                              hipStream_t stream) {
    const float* pf     = (const float*)d_in[0];
    const int*   coords = (const int*)d_in[1];
    float*       out    = (float*)d_out;

    const size_t map_bytes = (size_t)BB * NCELL * sizeof(u16);  // 3.43 MB

    if (ws_size >= map_bytes) {
        u16* map16 = (u16*)d_ws;

        ppsc_scatter_map<<<SNWG, GBLK, 0, stream>>>(coords, map16);
        ppsc_gather_all<<<GNWG, GBLK, 0, stream>>>(pf, map16, coords, out);
    } else {
        int n4_out = out_size / 4;
        ppsc_zero<<<(n4_out + 255) / 256, 256, 0, stream>>>(out, n4_out);

        int nsc = BB * PP * CC;              // 10,240,000
        ppsc_direct_scatter<<<(nsc + 255) / 256, 256, 0, stream>>>(pf, coords, out);
    }
}

// Round 12
// 94.589 us; speedup vs baseline: 1.3755x; 1.3755x over previous
//
#include <hip/hip_runtime.h>

// PointPillarScatter: out[b][c][y][x] = pf[b][p][c] where coords[b][p] = (b,0,y,x), else 0.
// B=8, P=20000, C=64, NX=432, NY=496. Output (8,64,496,432) fp32.
//
// R12 = R10 verbatim (best: 94.7 us). R11's 2-quad ILP variant regressed to
// 130 us (VGPR blowup/spills under launch_bounds(64,8)).
//
// Gather formulation (init-free):
//   K1 (scatter): map16[b][y*NX+x] = p    — no clearing pass.
//   K2 (gather): one thread per (b, 4-cell group); loops 16 channel-quads.
//       Reverse-check validation: entry q used only if q < P and coords[b][q]
//       maps back to this cell -> correct for arbitrary ws junk (poison/stale).
//       NT stores (R8 A/B: plain +21us). u16 map. 64-thr blocks.
//       Chunked XCD swizzle: 6696 = 8 x 837, one batch per XCD.
//       __launch_bounds__(64,8) + unroll 4: all ~26 blocks/CU co-resident.

#define BB    8
#define PP    20000
#define CC    64
#define NXX   432
#define NYY   496
#define NCELL (NXX * NYY)   /* 214272 */
#define NCELL4 (NCELL / 4)  /* 53568  */

#define GBLK   64
#define GNWG   ((BB * NCELL4) / GBLK)  /* 428544/64 = 6696 exactly */
#define NXCD   8
#define CHUNK  (GNWG / NXCD)           /* 837: exactly one batch per XCD */

typedef float f32x4 __attribute__((ext_vector_type(4)));
typedef unsigned short u16;
typedef u16 u16x4 __attribute__((ext_vector_type(4)));

__global__ void ppsc_scatter_map(const int* __restrict__ coords, u16* __restrict__ map16) {
    int t = blockIdx.x * blockDim.x + threadIdx.x;  // one thread per (b,p)
    if (t >= BB * PP) return;
    int b = t / PP;
    int p = t - b * PP;
    const int4 c4 = ((const int4*)coords)[t];       // [b, z, y, x] as int32
    int y = c4.z, x = c4.w;
    if ((unsigned)y < (unsigned)NYY && (unsigned)x < (unsigned)NXX)
        map16[(size_t)b * NCELL + y * NXX + x] = (u16)p;
}

// one thread per (b, cell-quad); all 64 channels.
__global__ void __launch_bounds__(GBLK, 8) ppsc_gather_all(const float* __restrict__ pf,
                                                           const u16* __restrict__ map16,
                                                           const int* __restrict__ coords,
                                                           float* __restrict__ out) {
    // chunked XCD swizzle: hardware bids round-robin XCDs; remap so XCD k owns
    // contiguous blocks [k*CHUNK,(k+1)*CHUNK) == exactly batch k.
    int bid = blockIdx.x;
    int wg  = (bid % NXCD) * CHUNK + bid / NXCD;

    int t  = wg * GBLK + threadIdx.x;
    int i4 = t % NCELL4;
    int b  = t / NCELL4;

    u16x4 m = ((const u16x4*)(map16 + (size_t)b * NCELL))[i4];
    const int4* cb = ((const int4*)coords) + (size_t)b * PP;
    int cell0 = i4 * 4;

    // reverse-validate each map entry: junk-proof, init-free.
    bool v0 = (m.x < PP), v1 = (m.y < PP), v2 = (m.z < PP), v3 = (m.w < PP);
    if (v0) { int4 c = cb[m.x]; v0 = (c.z * NXX + c.w) == cell0;     }
    if (v1) { int4 c = cb[m.y]; v1 = (c.z * NXX + c.w) == cell0 + 1; }
    if (v2) { int4 c = cb[m.z]; v2 = (c.z * NXX + c.w) == cell0 + 2; }
    if (v3) { int4 c = cb[m.w]; v3 = (c.z * NXX + c.w) == cell0 + 3; }

    const float* base = pf + (size_t)b * PP * CC;
    const float* p0 = base + (size_t)m.x * CC;
    const float* p1 = base + (size_t)m.y * CC;
    const float* p2 = base + (size_t)m.z * CC;
    const float* p3 = base + (size_t)m.w * CC;

    float* ob = out + (size_t)b * CC * NCELL + (size_t)cell0;

#pragma unroll 4
    for (int cq = 0; cq < 16; ++cq) {
        f32x4 o0 = (f32x4)0.f, o1 = (f32x4)0.f, o2 = (f32x4)0.f, o3 = (f32x4)0.f;
        if (v0) { f32x4 f = *(const f32x4*)(p0 + cq * 4);
                  o0.x = f.x; o1.x = f.y; o2.x = f.z; o3.x = f.w; }
        if (v1) { f32x4 f = *(const f32x4*)(p1 + cq * 4);
                  o0.y = f.x; o1.y = f.y; o2.y = f.z; o3.y = f.w; }
        if (v2) { f32x4 f = *(const f32x4*)(p2 + cq * 4);
                  o0.z = f.x; o1.z = f.y; o2.z = f.z; o3.z = f.w; }
        if (v3) { f32x4 f = *(const f32x4*)(p3 + cq * 4);
                  o0.w = f.x; o1.w = f.y; o2.w = f.z; o3.w = f.w; }
        float* op = ob + (size_t)(cq * 4) * NCELL;
        __builtin_nontemporal_store(o0, (f32x4*)op);
        __builtin_nontemporal_store(o1, (f32x4*)(op + (size_t)NCELL));
        __builtin_nontemporal_store(o2, (f32x4*)(op + 2 * (size_t)NCELL));
        __builtin_nontemporal_store(o3, (f32x4*)(op + 3 * (size_t)NCELL));
    }
}

// ---- fallback path (ws too small): zero output + direct scatter ----
__global__ void ppsc_zero(float* __restrict__ out, int n4) {
    int t = blockIdx.x * blockDim.x + threadIdx.x;
    if (t < n4) ((float4*)out)[t] = make_float4(0.f, 0.f, 0.f, 0.f);
}

__global__ void ppsc_direct_scatter(const float* __restrict__ pf,
                                    const int* __restrict__ coords,
                                    float* __restrict__ out) {
    int t = blockIdx.x * blockDim.x + threadIdx.x;  // one thread per (b,p,c)
    if (t >= BB * PP * CC) return;
    int c  = t % CC;
    int bp = t / CC;
    int b  = bp / PP;
    const int* cd = coords + (size_t)bp * 4;
    int y = cd[2], x = cd[3];
    if ((unsigned)y < (unsigned)NYY && (unsigned)x < (unsigned)NXX)
        out[((size_t)(b * CC + c)) * NCELL + (size_t)y * NXX + x] = pf[(size_t)bp * CC + c];
}

extern "C" void kernel_launch(void* const* d_in, const int* in_sizes, int n_in,
                              void* d_out, int out_size, void* d_ws, size_t ws_size,
                              hipStream_t stream) {
    const float* pf     = (const float*)d_in[0];
    const int*   coords = (const int*)d_in[1];
    float*       out    = (float*)d_out;

    const size_t map_bytes = (size_t)BB * NCELL * sizeof(u16);  // 3.43 MB

    if (ws_size >= map_bytes) {
        u16* map16 = (u16*)d_ws;

        int npil = BB * PP;                  // 160000
        ppsc_scatter_map<<<(npil + 255) / 256, 256, 0, stream>>>(coords, map16);

        ppsc_gather_all<<<GNWG, GBLK, 0, stream>>>(pf, map16, coords, out);
    } else {
        int n4_out = out_size / 4;
        ppsc_zero<<<(n4_out + 255) / 256, 256, 0, stream>>>(out, n4_out);

        int nsc = BB * PP * CC;              // 10,240,000
        ppsc_direct_scatter<<<(nsc + 255) / 256, 256, 0, stream>>>(pf, coords, out);
    }
}